// Round 1
// 371.260 us; speedup vs baseline: 1.0180x; 1.0180x over previous
//
#include <hip/hip_runtime.h>

typedef unsigned short u16;
typedef unsigned int u32;
typedef __attribute__((ext_vector_type(8))) short short8;
typedef __attribute__((ext_vector_type(4))) float f32x4;

#define NPIX 16384   // H*W per batch
#define LNEPS 1e-5f

__device__ __forceinline__ float bf2f(u16 u) {
  union { u32 i; float f; } x; x.i = ((u32)u) << 16; return x.f;
}
__device__ __forceinline__ u16 f2bf(float f) {
  union { float f; u32 i; } x; x.f = f;
  u32 r = x.i + 0x7fffu + ((x.i >> 16) & 1u);
  return (u16)(r >> 16);
}
__device__ __forceinline__ void gload_lds16(const void* g, void* l) {
  __builtin_amdgcn_global_load_lds((__attribute__((address_space(1))) void*)(g),
                                   (__attribute__((address_space(3))) void*)(l),
                                   16, 0, 0);
}
__device__ __forceinline__ uint4 pack8(float4 a, float4 b) {
  uint4 q;
  q.x = (u32)f2bf(a.x) | ((u32)f2bf(a.y) << 16);
  q.y = (u32)f2bf(a.z) | ((u32)f2bf(a.w) << 16);
  q.z = (u32)f2bf(b.x) | ((u32)f2bf(b.y) << 16);
  q.w = (u32)f2bf(b.z) | ((u32)f2bf(b.w) << 16);
  return q;
}

// ---------------- dtype probe: are inputs fp32 or bf16? ----------------
__global__ __launch_bounds__(256) void k_detect(const u16* __restrict__ x,
                                                int* __restrict__ flag) {
  float mx = 0.f;
  for (int i = threadIdx.x; i < 4096; i += 256) {
    float v = fabsf(bf2f(x[2 * i]));
    if (v == v) mx = fmaxf(mx, v);
  }
  for (int m = 1; m < 64; m <<= 1) mx = fmaxf(mx, __shfl_xor(mx, m));
  __shared__ float wmax[4];
  if ((threadIdx.x & 63) == 0) wmax[threadIdx.x >> 6] = mx;
  __syncthreads();
  if (threadIdx.x == 0) {
    float m2 = fmaxf(fmaxf(wmax[0], wmax[1]), fmaxf(wmax[2], wmax[3]));
    flag[0] = (m2 > 1e5f) ? 1 : 0;  // 1 == fp32 inputs
  }
}

// ------------- reorder weights: wkv[512][256] (k,v rows), wq[256][256] ----
__global__ __launch_bounds__(256) void k_wconv(
    const void* __restrict__ w, const void* __restrict__ bq,
    const void* __restrict__ klw, const void* __restrict__ klb,
    const void* __restrict__ vlw, const void* __restrict__ vlb,
    u16* __restrict__ wkv, u16* __restrict__ wq,
    float* __restrict__ bias_kv, float* __restrict__ lnw_kv,
    float* __restrict__ lnb_kv, float* __restrict__ bq_q,
    const int* __restrict__ flag) {
  const int i = blockIdx.x * 256 + threadIdx.x;
  const bool f32 = flag[0] != 0;
  auto getf = [&](const void* p, int j) -> float {
    return f32 ? ((const float*)p)[j] : bf2f(((const u16*)p)[j]);
  };
  if (i < 131072) {
    int o = i >> 8, c = i & 255;
    int h = o >> 5, tt = (o >> 4) & 1, d = o & 15;
    wkv[i] = f2bf(getf(w, (h * 48 + 16 + tt * 16 + d) * 256 + c));
  } else if (i < 196608) {
    int j = i - 131072; int r = j >> 8, c = j & 255;
    wq[j] = f2bf(getf(w, ((r >> 4) * 48 + (r & 15)) * 256 + c));
  } else if (i < 198400) {
    int j = i - 196608;
    if (j < 512) {
      int h = j >> 5, tt = (j >> 4) & 1, d = j & 15;
      bias_kv[j] = getf(bq, h * 48 + 16 + tt * 16 + d);
    } else if (j < 1024) {
      int o = j - 512; int h = o >> 5, tt = (o >> 4) & 1, d = o & 15;
      lnw_kv[o] = getf(tt ? vlw : klw, h * 16 + d);
    } else if (j < 1536) {
      int o = j - 1024; int h = o >> 5, tt = (o >> 4) & 1, d = o & 15;
      lnb_kv[o] = getf(tt ? vlb : klb, h * 16 + d);
    } else {
      int r = j - 1536;
      bq_q[r] = getf(bq, (r >> 4) * 48 + (r & 15));
    }
  }
}

// -------- K1: kv-GEMM. 512 thr; tile = 256 kv-ch (hg half) x 128 px -------
// 8 waves: wave = 128 ch (hl=wv&1) x 32 px (pxq=wv>>1). acc[8][2] = 64 VGPR.
// Double-buffered LDS, one barrier per k-step; XOR-swizzled frag layouts via
// pre-swizzled global sources (LDS stays gload_lds-linear).
__global__ __launch_bounds__(512, 4) void k_gemm1(
    const void* __restrict__ xin, const u16* __restrict__ wkv,
    const float* __restrict__ bias_kv, const float* __restrict__ lnw_kv,
    const float* __restrict__ lnb_kv, float* __restrict__ kvpart,
    const int* __restrict__ flag) {
  // union: [w dbuf 32K | x dbuf 16K] overlapped with klds 65K; + bls/wls/lls + tmp
  __shared__ alignas(16) char shraw[73728];
  u16 (*wlds)[256][32] = (u16 (*)[256][32])shraw;            // [2][256][32]
  u16 (*xlds)[32][128] = (u16 (*)[32][128])(shraw + 32768);  // [2][32][128]
  u16 (*klds)[260]     = (u16 (*)[260])shraw;                // [128][260]
  float* bls = (float*)(shraw + 66560);
  float* wls = bls + 256;
  float* lls = bls + 512;
  float (*tmp)[256] = (float (*)[256])(shraw + 69632);       // [4][256]

  const int t = threadIdx.x;
  // XCD-aware bijective swizzle: nwg=2048, chunk=256 per XCD
  const int lbid = ((blockIdx.x & 7) << 8) + (blockIdx.x >> 3);
  const int hg = lbid & 1;
  const int pc = (lbid >> 1) & 127;
  const int b  = lbid >> 8;
  const int p0 = pc * 128;
  const int wv = t >> 6, lane = t & 63, quad = lane >> 4, l16 = lane & 15;
  const int hl = wv & 1, pxq = wv >> 1;
  const bool f32 = flag[0] != 0;

  if (t < 256) {
    bls[t] = bias_kv[hg * 256 + t];
    wls[t] = lnw_kv[hg * 256 + t];
    lls[t] = lnb_kv[hg * 256 + t];
  }

  f32x4 acc[8][2];
#pragma unroll
  for (int ms = 0; ms < 8; ++ms) {
    acc[ms][0] = (f32x4){0.f, 0.f, 0.f, 0.f};
    acc[ms][1] = (f32x4){0.f, 0.f, 0.f, 0.f};
  }

  // --- staging geometry (per thread), swizzled global sources ---
  const int wrow = t >> 2;                        // W tile row (+128*i)
  const int wcs  = t & 3;                         // LDS k-chunk slot
  const int wks  = (wcs ^ ((t >> 3) & 3)) * 8;    // swizzled k offset in 32
  const u16* wsrc = wkv + ((size_t)(hg * 256 + wrow) * 256 + wks);

  const int xrow = t >> 4;                                  // x tile row 0..31
  const int xg   = (t & 15) ^ ((xrow >> 3) << 1);           // swizzled px-chunk
  const u16* xsrc_bf = (const u16*)xin +
      ((size_t)(b * 256 + xrow) * NPIX + p0 + xg * 8);
  const float* xsrc_f = (const float*)xin +
      ((size_t)(b * 256 + xrow) * NPIX + p0 + xg * 8);

  // --- prologue: stage ks=0 into buffer 0 ---
  gload_lds16(wsrc, &wlds[0][wrow][wcs * 8]);
  gload_lds16(wsrc + (size_t)128 * 256, &wlds[0][128 + wrow][wcs * 8]);
  if (!f32) {
    gload_lds16(xsrc_bf, &xlds[0][xrow][(t & 15) * 8]);
  } else {
    float4 a = *(const float4*)xsrc_f;
    float4 c = *(const float4*)(xsrc_f + 4);
    *(uint4*)&xlds[0][xrow][(t & 15) * 8] = pack8(a, c);
  }
  __syncthreads();

  for (int ks = 0; ks < 8; ++ks) {
    const int cur = ks & 1, nxt = cur ^ 1;
    const bool more = ks < 7;
    float4 v0, v1;
    if (more) {
      const u16* ws = wsrc + (ks + 1) * 32;
      gload_lds16(ws, &wlds[nxt][wrow][wcs * 8]);
      gload_lds16(ws + (size_t)128 * 256, &wlds[nxt][128 + wrow][wcs * 8]);
      if (!f32) {
        gload_lds16(xsrc_bf + (size_t)(ks + 1) * 32 * NPIX,
                    &xlds[nxt][xrow][(t & 15) * 8]);
      } else {
        const float* xf = xsrc_f + (size_t)(ks + 1) * 32 * NPIX;
        v0 = *(const float4*)xf;
        v1 = *(const float4*)(xf + 4);
      }
    }
    // ---- compute current buffer ----
    short8 bfr[2];
#pragma unroll
    for (int ns = 0; ns < 2; ++ns) {
      const int pxn = pxq * 32 + ns * 16 + l16;
      const int cs8 = ((((pxn >> 3) ^ (quad << 1)) << 3) + (pxn & 7));
      short8 bv;
#pragma unroll
      for (int j = 0; j < 8; ++j)
        bv[j] = (short)xlds[cur][quad * 8 + j][cs8];
      bfr[ns] = bv;
    }
#pragma unroll
    for (int ms = 0; ms < 8; ++ms) {
      const int row = hl * 128 + ms * 16 + l16;
      short8 av = *(const short8*)&wlds[cur][row][(quad ^ ((l16 >> 1) & 3)) * 8];
      acc[ms][0] = __builtin_amdgcn_mfma_f32_16x16x32_bf16(av, bfr[0], acc[ms][0], 0, 0, 0);
      acc[ms][1] = __builtin_amdgcn_mfma_f32_16x16x32_bf16(av, bfr[1], acc[ms][1], 0, 0, 0);
    }
    if (more && f32)
      *(uint4*)&xlds[nxt][xrow][(t & 15) * 8] = pack8(v0, v1);
    __syncthreads();
  }

  // ---- epilogue: 2 phases x 4 heads. klds slot = (j>>1) | (hl<<1) ----
#pragma unroll
  for (int p = 0; p < 2; ++p) {
    __syncthreads();
#pragma unroll
    for (int j = 0; j < 4; ++j) {
      const int msl = p * 4 + j;
      const int slot = (j >> 1) | (hl << 1);
      const int cb = slot * 64 + (j & 1) * 16;   // {k:0,v:16}; lo at +32/+48
      float4 bi = *(const float4*)&bls[hl * 128 + msl * 16 + quad * 4];
      float4 lw = *(const float4*)&wls[hl * 128 + msl * 16 + quad * 4];
      float4 lb = *(const float4*)&lls[hl * 128 + msl * 16 + quad * 4];
      float biv[4] = {bi.x, bi.y, bi.z, bi.w};
      float lwv[4] = {lw.x, lw.y, lw.z, lw.w};
      float lbv[4] = {lb.x, lb.y, lb.z, lb.w};
#pragma unroll
      for (int ns = 0; ns < 2; ++ns) {
        const int px = pxq * 32 + ns * 16 + l16;
        float x0[4];
#pragma unroll
        for (int r = 0; r < 4; ++r) x0[r] = acc[msl][ns][r] + biv[r];
        float s1 = x0[0] + x0[1] + x0[2] + x0[3];
        s1 += __shfl_xor(s1, 16);
        s1 += __shfl_xor(s1, 32);
        float mean = s1 * (1.0f / 16.0f);
        float dv[4];
#pragma unroll
        for (int r = 0; r < 4; ++r) dv[r] = x0[r] - mean;
        float s2 = dv[0]*dv[0] + dv[1]*dv[1] + dv[2]*dv[2] + dv[3]*dv[3];
        s2 += __shfl_xor(s2, 16);
        s2 += __shfl_xor(s2, 32);
        float var = s2 * (1.0f / 15.0f);           // ddof=1
        float rstd = 1.0f / (sqrtf(var) + LNEPS);
        u16 hi[4], lo[4];
#pragma unroll
        for (int r = 0; r < 4; ++r) {
          float kn = dv[r] * rstd * lwv[r] + lbv[r];  // f32, unrounded
          hi[r] = f2bf(kn);
          lo[r] = f2bf(kn - bf2f(hi[r]));             // Dekker residual
        }
        uint2 ph, pl;
        ph.x = (u32)hi[0] | ((u32)hi[1] << 16);
        ph.y = (u32)hi[2] | ((u32)hi[3] << 16);
        pl.x = (u32)lo[0] | ((u32)lo[1] << 16);
        pl.y = (u32)lo[2] | ((u32)lo[3] << 16);
        *(uint2*)&klds[px][cb + quad * 4] = ph;
        *(uint2*)&klds[px][cb + 32 + quad * 4] = pl;
      }
    }
    __syncthreads();
    // kv = khi.vhi + khi.vlo + klo.vhi; wave role (slot4, combo)
    const int slot4 = wv >> 1, combo = wv & 1;
    const int cb2 = slot4 * 64;
    f32x4 kva = (f32x4){0.f, 0.f, 0.f, 0.f};
    if (combo == 0) {
#pragma unroll
      for (int px2 = 0; px2 < 4; ++px2) {
        short8 av, bv;
#pragma unroll
        for (int jj = 0; jj < 8; ++jj) {
          av[jj] = (short)klds[px2 * 32 + quad * 8 + jj][cb2 + l16];        // khi
          bv[jj] = (short)klds[px2 * 32 + quad * 8 + jj][cb2 + 16 + l16];   // vhi
        }
        kva = __builtin_amdgcn_mfma_f32_16x16x32_bf16(av, bv, kva, 0, 0, 0);
      }
    } else {
#pragma unroll
      for (int px2 = 0; px2 < 4; ++px2) {
        short8 ah, al, vh, vl;
#pragma unroll
        for (int jj = 0; jj < 8; ++jj) {
          const int px = px2 * 32 + quad * 8 + jj;
          ah[jj] = (short)klds[px][cb2 + l16];        // khi
          vh[jj] = (short)klds[px][cb2 + 16 + l16];   // vhi
          al[jj] = (short)klds[px][cb2 + 32 + l16];   // klo
          vl[jj] = (short)klds[px][cb2 + 48 + l16];   // vlo
        }
        kva = __builtin_amdgcn_mfma_f32_16x16x32_bf16(ah, vl, kva, 0, 0, 0);
        kva = __builtin_amdgcn_mfma_f32_16x16x32_bf16(al, vh, kva, 0, 0, 0);
      }
    }
    __syncthreads();
    if (combo) {
#pragma unroll
      for (int r = 0; r < 4; ++r) tmp[slot4][(quad * 4 + r) * 16 + l16] = kva[r];
    }
    __syncthreads();
    if (!combo) {
      // head within hg: h = (slot4>>1)*4 + p*2 + (slot4&1)
      const int h = (slot4 >> 1) * 4 + p * 2 + (slot4 & 1);
      float* kvp = kvpart +
          ((size_t)(((b * 128 + pc) * 2 + hg) * 8 + h) << 8);
#pragma unroll
      for (int r = 0; r < 4; ++r) {
        const int idx = (quad * 4 + r) * 16 + l16;
        kvp[idx] = kva[r] + tmp[slot4][idx];
      }
    }
  }
}

// ------ deterministic kv reduction: kvg[b][h][de] = (1/N) * sum_pc partials
__global__ __launch_bounds__(256) void k_reduce(const float* __restrict__ kvpart,
                                                float* __restrict__ kvg) {
  const int t = threadIdx.x;
  const int b = blockIdx.x >> 4, h = blockIdx.x & 15;
  const int hg = h >> 3, hl = h & 7;
  const float* src = kvpart + ((size_t)((b * 128 * 2 + hg) * 8 + hl) << 8) + t;
  float s = 0.f;
  for (int pc = 0; pc < 128; ++pc)
    s += src[(size_t)pc * (2 * 8 * 256)];
  kvg[((size_t)blockIdx.x << 8) + t] = s * (1.0f / 16384.0f);
}

// ------- fold kv into q-weights (f32), store Dekker hi/lo bf16 pair -------
__global__ __launch_bounds__(256) void k_fold(const u16* __restrict__ wq,
                                              const float* __restrict__ bq_q,
                                              const float* __restrict__ kvg,
                                              u16* __restrict__ whi,
                                              u16* __restrict__ wlo,
                                              float* __restrict__ beff) {
  __shared__ float kvs[256];
  __shared__ float qb[16];
  const int t = threadIdx.x;
  const int b = blockIdx.x >> 4, h = blockIdx.x & 15;
  kvs[t] = kvg[((size_t)blockIdx.x << 8) + t];
  if (t < 16) qb[t] = bq_q[h * 16 + t];
  __syncthreads();
  const int e = t >> 4, c0 = (t & 15) * 16;
  float o[16];
#pragma unroll
  for (int c = 0; c < 16; ++c) o[c] = 0.f;
  for (int d = 0; d < 16; ++d) {
    float kv_de = kvs[d * 16 + e];
    const u16* wr = wq + (size_t)(h * 16 + d) * 256 + c0;
#pragma unroll
    for (int c = 0; c < 16; ++c) o[c] = fmaf(bf2f(wr[c]), kv_de, o[c]);
  }
  const size_t wbase = (size_t)(b * 256 + h * 16 + e) * 256 + c0;
#pragma unroll
  for (int c = 0; c < 16; ++c) {
    u16 hi = f2bf(o[c]);
    whi[wbase + c] = hi;
    wlo[wbase + c] = f2bf(o[c] - bf2f(hi));
  }
  if (t < 16) {
    float s = 0.f;
    for (int d = 0; d < 16; ++d) s += qb[d] * kvs[d * 16 + t];
    beff[b * 256 + h * 16 + t] = s;
  }
}

// -------- K2: out = x . (Whi+Wlo)^T + beff -> (B,256,N) channel-major ------
// 512 thr, wave = 128 ch x 32 px, acc[8][2]. x double-buffered (1-deep
// prefetch), W single-buffered (L2-resident) staged between barriers.
__global__ __launch_bounds__(512, 4) void k_gemm2(
    const void* __restrict__ xin, const u16* __restrict__ whi,
    const u16* __restrict__ wlo, const float* __restrict__ beff,
    void* __restrict__ outv, const int* __restrict__ flag) {
  __shared__ alignas(16) char shraw[49152];
  u16 (*wldh)[32] = (u16 (*)[32])shraw;                     // [256][32]
  u16 (*wldl)[32] = (u16 (*)[32])(shraw + 16384);           // [256][32]
  u16 (*xlds)[32][128] = (u16 (*)[32][128])(shraw + 32768); // [2][32][128]

  const int t = threadIdx.x;
  // XCD-aware bijective swizzle: nwg=1024, chunk=128 per XCD
  const int lbid = ((blockIdx.x & 7) << 7) + (blockIdx.x >> 3);
  const int pc = lbid & 127;
  const int b  = lbid >> 7;
  const int p0 = pc * 128;
  const int wv = t >> 6, lane = t & 63, quad = lane >> 4, l16 = lane & 15;
  const int hl = wv & 1, pxq = wv >> 1;
  const bool f32 = flag[0] != 0;

  f32x4 acc[8][2];
#pragma unroll
  for (int ms = 0; ms < 8; ++ms) {
    acc[ms][0] = (f32x4){0.f, 0.f, 0.f, 0.f};
    acc[ms][1] = (f32x4){0.f, 0.f, 0.f, 0.f};
  }

  const int wrow = t >> 2;
  const int wcs  = t & 3;
  const int wks  = (wcs ^ ((t >> 3) & 3)) * 8;
  const size_t wbase = (size_t)(b * 256 + wrow) * 256 + wks;
  const u16* wsrch = whi + wbase;
  const u16* wsrcl = wlo + wbase;

  const int xrow = t >> 4;
  const int xg   = (t & 15) ^ ((xrow >> 3) << 1);
  const u16* xsrc_bf = (const u16*)xin +
      ((size_t)(b * 256 + xrow) * NPIX + p0 + xg * 8);
  const float* xsrc_f = (const float*)xin +
      ((size_t)(b * 256 + xrow) * NPIX + p0 + xg * 8);

  // --- prologue: stage W(0) and x(0) ---
  gload_lds16(wsrch, &wldh[wrow][wcs * 8]);
  gload_lds16(wsrch + (size_t)128 * 256, &wldh[128 + wrow][wcs * 8]);
  gload_lds16(wsrcl, &wldl[wrow][wcs * 8]);
  gload_lds16(wsrcl + (size_t)128 * 256, &wldl[128 + wrow][wcs * 8]);
  if (!f32) {
    gload_lds16(xsrc_bf, &xlds[0][xrow][(t & 15) * 8]);
  } else {
    float4 a = *(const float4*)xsrc_f;
    float4 c = *(const float4*)(xsrc_f + 4);
    *(uint4*)&xlds[0][xrow][(t & 15) * 8] = pack8(a, c);
  }
  __syncthreads();

  for (int ks = 0; ks < 8; ++ks) {
    const int cur = ks & 1, nxt = cur ^ 1;
    const bool more = ks < 7;
    float4 v0, v1;
    if (more) {
      if (!f32) {
        gload_lds16(xsrc_bf + (size_t)(ks + 1) * 32 * NPIX,
                    &xlds[nxt][xrow][(t & 15) * 8]);
      } else {
        const float* xf = xsrc_f + (size_t)(ks + 1) * 32 * NPIX;
        v0 = *(const float4*)xf;
        v1 = *(const float4*)(xf + 4);
      }
    }
    // ---- compute ----
    short8 bfr[2];
#pragma unroll
    for (int ns = 0; ns < 2; ++ns) {
      const int pxn = pxq * 32 + ns * 16 + l16;
      const int cs8 = ((((pxn >> 3) ^ (quad << 1)) << 3) + (pxn & 7));
      short8 bv;
#pragma unroll
      for (int j = 0; j < 8; ++j)
        bv[j] = (short)xlds[cur][quad * 8 + j][cs8];
      bfr[ns] = bv;
    }
#pragma unroll
    for (int ms = 0; ms < 8; ++ms) {
      const int row = hl * 128 + ms * 16 + l16;
      const int csw = (quad ^ ((l16 >> 1) & 3)) * 8;
      short8 avh = *(const short8*)&wldh[row][csw];
      short8 avl = *(const short8*)&wldl[row][csw];
      acc[ms][0] = __builtin_amdgcn_mfma_f32_16x16x32_bf16(avh, bfr[0], acc[ms][0], 0, 0, 0);
      acc[ms][0] = __builtin_amdgcn_mfma_f32_16x16x32_bf16(avl, bfr[0], acc[ms][0], 0, 0, 0);
      acc[ms][1] = __builtin_amdgcn_mfma_f32_16x16x32_bf16(avh, bfr[1], acc[ms][1], 0, 0, 0);
      acc[ms][1] = __builtin_amdgcn_mfma_f32_16x16x32_bf16(avl, bfr[1], acc[ms][1], 0, 0, 0);
    }
    __syncthreads();               // everyone done reading W tile ks
    if (more) {
      const u16* wh = wsrch + (ks + 1) * 32;
      const u16* wl = wsrcl + (ks + 1) * 32;
      gload_lds16(wh, &wldh[wrow][wcs * 8]);
      gload_lds16(wh + (size_t)128 * 256, &wldh[128 + wrow][wcs * 8]);
      gload_lds16(wl, &wldl[wrow][wcs * 8]);
      gload_lds16(wl + (size_t)128 * 256, &wldl[128 + wrow][wcs * 8]);
      if (f32)
        *(uint4*)&xlds[nxt][xrow][(t & 15) * 8] = pack8(v0, v1);
      __syncthreads();             // W(ks+1) + x(ks+1) ready
    }
  }

  const size_t obase = (size_t)b * 256 * NPIX + p0;
#pragma unroll
  for (int ms = 0; ms < 8; ++ms) {
    const int o0 = hl * 128 + ms * 16 + quad * 4;
    float4 be = *(const float4*)&beff[b * 256 + o0];
    float bev[4] = {be.x, be.y, be.z, be.w};
#pragma unroll
    for (int ns = 0; ns < 2; ++ns) {
      const int px = pxq * 32 + ns * 16 + l16;
#pragma unroll
      for (int r = 0; r < 4; ++r) {
        const int o = o0 + r;
        float val = acc[ms][ns][r] + bev[r];
        if (f32) ((float*)outv)[obase + (size_t)o * NPIX + px] = val;
        else ((u16*)outv)[obase + (size_t)o * NPIX + px] = f2bf(val);
      }
    }
  }
}

// ---------------- launch ----------------
extern "C" void kernel_launch(void* const* d_in, const int* in_sizes, int n_in,
                              void* d_out, int out_size, void* d_ws, size_t ws_size,
                              hipStream_t stream) {
  (void)in_sizes; (void)n_in; (void)out_size; (void)ws_size;
  char* ws = (char*)d_ws;
  u16* wkv       = (u16*)(ws + 0);         // 262144
  u16* wq        = (u16*)(ws + 262144);    // 131072
  u16* weff_hi   = (u16*)(ws + 393216);    // 1048576
  u16* weff_lo   = (u16*)(ws + 1441792);   // 1048576
  float* kvg     = (float*)(ws + 2490368); // 131072
  float* bias_kv = (float*)(ws + 2621440); // 2048
  float* lnw_kv  = (float*)(ws + 2623488); // 2048
  float* lnb_kv  = (float*)(ws + 2625536); // 2048
  float* bq_q    = (float*)(ws + 2627584); // 1024
  float* beff    = (float*)(ws + 2628608); // 8192
  int* flag      = (int*)(ws + 2636800);   // 4
  float* kvpart  = (float*)(ws + 4194304); // 16777216

  k_detect<<<1, 256, 0, stream>>>((const u16*)d_in[0], flag);
  k_wconv<<<775, 256, 0, stream>>>(d_in[1], d_in[2], d_in[3], d_in[4], d_in[5],
                                   d_in[6], wkv, wq, bias_kv, lnw_kv, lnb_kv,
                                   bq_q, flag);
  k_gemm1<<<2048, 512, 0, stream>>>(d_in[0], wkv, bias_kv, lnw_kv, lnb_kv,
                                    kvpart, flag);
  k_reduce<<<128, 256, 0, stream>>>(kvpart, kvg);
  k_fold<<<128, 256, 0, stream>>>(wq, bq_q, kvg, weff_hi, weff_lo, beff);
  k_gemm2<<<1024, 512, 0, stream>>>(d_in[0], weff_hi, weff_lo, beff, d_out, flag);
}